// Round 1
// baseline (356.685 us; speedup 1.0000x reference)
//
#include <hip/hip_runtime.h>

// SimpleHashEncoder1D: out[n, l*2+f] = hash_table[floor(xn*scale[l]+0.5) & (T-1)][f]
// xn = (x+bound)/(2*bound), scale[l] = 16*b^l - 1, b = expf((logf(2^19)-logf(16))/15)
//
// float32 bit-exactness analysis (must match numpy ref exactly — any index
// mismatch is ~1e-3 error vs 2e-5 threshold):
//   b = 0x3FFFFFFF = 2 - 2^-23   (NOT 2.0: correctly-rounded f32 log/exp chain)
//   fl32(b^l) = 2^l * (1 - l*2^-24)            (exact, powf margin ~6e-6 ulp)
//   scale[l]  = (2^(l+4) - 1) - l*2^(l-20)     (exactly representable)
//   bits(scale[l]) = ((130+l)<<23) | (0x800000 - (0x100000>>l) - l)
// Separate mul/add via __fmul_rn/__fadd_rn (numpy does not fuse); __fdiv_rn for
// the normalize. Indices provably in [0, 2^19) -> '& (T-1)' == '% T'.

constexpr int T_SIZE = 524288;   // 2^19
constexpr int N_PTS  = 2097152;  // 2^21

__device__ __forceinline__ float scale_for_level(int l) {
    unsigned bits = ((130u + (unsigned)l) << 23)
                  | (0x800000u - (0x100000u >> l) - (unsigned)l);
    return __uint_as_float(bits);
}

__global__ __launch_bounds__(256) void hash_encode_kernel(
    const float* __restrict__ x,
    const float* __restrict__ table,
    const int* __restrict__ bound_p,
    float* __restrict__ out)
{
    int tid = blockIdx.x * 256 + threadIdx.x;   // 2^24 threads total
    int n = tid >> 3;        // point index
    int j = tid & 7;         // this thread handles levels 2j, 2j+1

    float fb = (float)bound_p[0];
    float xv = x[n];
    // xn = (x + bound) / (2*bound), all correctly-rounded f32, no contraction
    float xn = __fdiv_rn(__fadd_rn(xv, fb), __fmul_rn(2.0f, fb));

    int l0 = j << 1;
    float s0 = scale_for_level(l0);
    float s1 = scale_for_level(l0 + 1);

    float xs0 = __fadd_rn(__fmul_rn(xn, s0), 0.5f);
    float xs1 = __fadd_rn(__fmul_rn(xn, s1), 0.5f);

    // xs >= 0.5 always, so int-trunc == floor; result < 2^19 so & is exact mod
    int i0 = ((int)xs0) & (T_SIZE - 1);
    int i1 = ((int)xs1) & (T_SIZE - 1);

    const float2* t2 = (const float2*)table;
    float2 a = t2[i0];
    float2 b = t2[i1];

    float4 o;
    o.x = a.x; o.y = a.y; o.z = b.x; o.w = b.y;
    ((float4*)out)[tid] = o;   // consecutive lanes -> consecutive 16B: coalesced
}

extern "C" void kernel_launch(void* const* d_in, const int* in_sizes, int n_in,
                              void* d_out, int out_size, void* d_ws, size_t ws_size,
                              hipStream_t stream) {
    const float* x     = (const float*)d_in[0];
    const float* table = (const float*)d_in[1];
    const int*   bound = (const int*)d_in[2];
    float* out = (float*)d_out;

    int total_threads = N_PTS * 8;              // 2^24
    int blocks = total_threads / 256;           // 65536
    hash_encode_kernel<<<blocks, 256, 0, stream>>>(x, table, bound, out);
}

// Round 3
// 346.009 us; speedup vs baseline: 1.0309x; 1.0309x over previous
//
#include <hip/hip_runtime.h>

// SimpleHashEncoder1D: out[n, l*2+f] = hash_table[floor(xn*scale[l]+0.5) & (T-1)][f]
// xn = (x+bound)/(2*bound), scale[l] = 16*b^l - 1, b = expf((logf(2^19)-logf(16))/15)
//
// float32 bit-exactness (verified R1, absmax == 0.0):
//   b = 0x3FFFFFFF = 2 - 2^-23   (NOT 2.0: correctly-rounded f32 log/exp chain)
//   fl32(b^l) = 2^l * (1 - l*2^-24)            (exact)
//   scale[l]  = (2^(l+4) - 1) - l*2^(l-20)     (exactly representable)
//   bits(scale[l]) = ((130+l)<<23) | (0x800000 - (0x100000>>l) - l)
// Separate mul/add (numpy does not fuse); __fdiv_rn for the normalize.
// Indices provably in [0, 2^19) -> '& (T-1)' == '% T'.
//
// R3: same as R2 (nt stores so the 4 MiB table == one XCD L2 stays resident
// against the 256 MiB write stream) but using a clang native vector type for
// __builtin_nontemporal_store — HIP's float4 is a class and the builtin
// rejects it.

constexpr int T_SIZE = 524288;   // 2^19
constexpr int N_PTS  = 2097152;  // 2^21

typedef float vfloat4 __attribute__((ext_vector_type(4)));

__device__ __forceinline__ float scale_for_level(int l) {
    unsigned bits = ((130u + (unsigned)l) << 23)
                  | (0x800000u - (0x100000u >> l) - (unsigned)l);
    return __uint_as_float(bits);
}

__global__ __launch_bounds__(256) void hash_encode_kernel(
    const float* __restrict__ x,
    const float* __restrict__ table,
    const int* __restrict__ bound_p,
    float* __restrict__ out)
{
    int tid = blockIdx.x * 256 + threadIdx.x;   // 2^24 threads total
    int n = tid >> 3;        // point index
    int j = tid & 7;         // this thread handles levels 2j, 2j+1

    float fb = (float)bound_p[0];
    float xv = __builtin_nontemporal_load(&x[n]);   // streamed once, don't cache
    // xn = (x + bound) / (2*bound), all correctly-rounded f32, no contraction
    float xn = __fdiv_rn(__fadd_rn(xv, fb), __fmul_rn(2.0f, fb));

    int l0 = j << 1;
    float s0 = scale_for_level(l0);
    float s1 = scale_for_level(l0 + 1);

    float xs0 = __fadd_rn(__fmul_rn(xn, s0), 0.5f);
    float xs1 = __fadd_rn(__fmul_rn(xn, s1), 0.5f);

    // xs >= 0.5 always, so int-trunc == floor; result < 2^19 so & is exact mod
    int i0 = ((int)xs0) & (T_SIZE - 1);
    int i1 = ((int)xs1) & (T_SIZE - 1);

    const float2* t2 = (const float2*)table;
    float2 a = t2[i0];    // cached: table must stay L2-resident
    float2 b = t2[i1];

    vfloat4 o;
    o.x = a.x; o.y = a.y; o.z = b.x; o.w = b.y;
    // nt store: stream past L2, don't evict the table
    __builtin_nontemporal_store(o, (vfloat4*)out + tid);
}

extern "C" void kernel_launch(void* const* d_in, const int* in_sizes, int n_in,
                              void* d_out, int out_size, void* d_ws, size_t ws_size,
                              hipStream_t stream) {
    const float* x     = (const float*)d_in[0];
    const float* table = (const float*)d_in[1];
    const int*   bound = (const int*)d_in[2];
    float* out = (float*)d_out;

    int total_threads = N_PTS * 8;              // 2^24
    int blocks = total_threads / 256;           // 65536
    hash_encode_kernel<<<blocks, 256, 0, stream>>>(x, table, bound, out);
}